// Round 2
// baseline (129.552 us; speedup 1.0000x reference)
//
#include <hip/hip_runtime.h>

// NetVLAD: N=16, C=1024, P=1024, K=32. MFMA bf16 for both GEMMs (NT layout).
// Runtime dtype detection (fp32 vs bf16 inputs); fp32 accumulate throughout.
// This rev: shared-mem hoisted out of templated bodies (was duplicated per
// instantiation -> 85KB/block -> 1 blk/CU!); 64-wide chunks (LDS 27K/19K);
// depth-2 register prefetch with named sets; per-block dtype detect (k_detect
// gone); asum/ssq as per-block partial stores (no atomics, no memset).
// 3 dispatches total.
#define NB   16
#define CC   1024
#define PP   1024
#define KK   32
#define EPSF 1e-12f

typedef __attribute__((ext_vector_type(8))) short  bf16x8;
typedef __attribute__((ext_vector_type(4))) float  f32x4;

__device__ __forceinline__ float bf2f(unsigned short u) {
    union { unsigned int i; float f; } v; v.i = ((unsigned int)u) << 16; return v.f;
}
__device__ __forceinline__ unsigned short f2bf(float f) {
    union { float f; unsigned int i; } v; v.f = f;
    return (unsigned short)((v.i + 0x7fffu + ((v.i >> 16) & 1u)) >> 16);  // RNE
}

template <typename T> struct IO;
template <> struct IO<float> {
    static __device__ __forceinline__ float  ld (const float* p) { return *p; }
    static __device__ __forceinline__ float4 ld4(const float* p) { return *(const float4*)p; }
};
template <> struct IO<unsigned short> {
    static __device__ __forceinline__ float  ld (const unsigned short* p) { return bf2f(*p); }
    static __device__ __forceinline__ float4 ld4(const unsigned short* p) {
        const ushort4 u = *(const ushort4*)p;
        return make_float4(bf2f(u.x), bf2f(u.y), bf2f(u.z), bf2f(u.w));
    }
};

// Workgroup barrier WITHOUT the __syncthreads vmcnt(0) drain: each wave waits
// only its own LDS ops (lgkmcnt), so prefetch global loads stay in flight
// across the barrier.
__device__ __forceinline__ void wg_sync_fast() {
    asm volatile("s_waitcnt lgkmcnt(0)" ::: "memory");
    __builtin_amdgcn_s_barrier();
    asm volatile("" ::: "memory");
}

// ---------------------------------------------------------------------------
// K1 (k_attn): per (n, 32-px tile). 16 chunks of 64c, double-buffered LDS,
// depth-2 register prefetch. Per-px sumsq, MFMA logits (M=32px,N=32k,K=1024c),
// scale by rnorm, softmax over k, write attn bf16 + asum partial + rnorm.
// grid 512 = n*32 + pt, block 256. Dtype detect done per-block.
// ---------------------------------------------------------------------------
struct AttnSmem {
    unsigned short xt[2][32 * 72];   // [buf][px][c] (72-pad, 144B rows)
    unsigned short wl[2][32 * 72];   // [buf][k][c]
    float red[32 * 32];              // [c-row][px]
    float lg[32 * 33];               // [px][k]
    float inv[32];
    float rnorm[32];
};

template <typename T>
__device__ __forceinline__ void attn_body(const T* __restrict__ x,
                                          const T* __restrict__ w,
                                          float* __restrict__ rnorm_ws,
                                          unsigned short* __restrict__ attn_g,
                                          float* __restrict__ asum_part,
                                          AttnSmem& sm) {
    const int b = blockIdx.x, t = threadIdx.x;
    const int n = b >> 5, pt = b & 31, pbase = pt * 32;
    const int lane = t & 63, wid = t >> 6;
    const int quad = lane >> 4, l15 = lane & 15;
    const int mt = wid & 1, nt = wid >> 1;   // wave -> (px-tile, k-tile)

    const size_t xb = (size_t)n * CC * PP + pbase;
    const int pxg  = 4 * (t & 7);     // this thread's 4 pixels (local)
    const int crow = t >> 3;          // c-row 0..31 (also W k-row)
    const int wcg  = (t & 7) * 8;     // W staging: 8 c's

    float ss0 = 0.f, ss1 = 0.f, ss2 = 0.f, ss3 = 0.f;
    f32x4 acc = {0.f, 0.f, 0.f, 0.f};

    // two named prefetch register sets (depth-2 pipeline)
    float4 xr0[2], xr1[2], wr0[2], wr1[2];
    xr0[0] = IO<T>::ld4(&x[xb + (size_t)(crow)      * PP + pxg]);
    xr0[1] = IO<T>::ld4(&x[xb + (size_t)(crow + 32) * PP + pxg]);
    wr0[0] = IO<T>::ld4(&w[crow * CC + wcg]);
    wr0[1] = IO<T>::ld4(&w[crow * CC + wcg + 4]);
    xr1[0] = IO<T>::ld4(&x[xb + (size_t)(64 + crow)      * PP + pxg]);
    xr1[1] = IO<T>::ld4(&x[xb + (size_t)(64 + crow + 32) * PP + pxg]);
    wr1[0] = IO<T>::ld4(&w[crow * CC + 64 + wcg]);
    wr1[1] = IO<T>::ld4(&w[crow * CC + 64 + wcg + 4]);

#define ATTN_STEP(CH, XR, WR)                                                     \
    do {                                                                          \
        const int buf = (CH) & 1;                                                 \
        _Pragma("unroll")                                                         \
        for (int pass = 0; pass < 2; ++pass) {                                    \
            const int cl = crow + 32 * pass;                                      \
            const float4 v = XR[pass];                                            \
            ss0 += v.x * v.x; ss1 += v.y * v.y;                                   \
            ss2 += v.z * v.z; ss3 += v.w * v.w;                                   \
            sm.xt[buf][(pxg + 0) * 72 + cl] = f2bf(v.x);                          \
            sm.xt[buf][(pxg + 1) * 72 + cl] = f2bf(v.y);                          \
            sm.xt[buf][(pxg + 2) * 72 + cl] = f2bf(v.z);                          \
            sm.xt[buf][(pxg + 3) * 72 + cl] = f2bf(v.w);                          \
        }                                                                         \
        _Pragma("unroll")                                                         \
        for (int j = 0; j < 2; ++j) {                                             \
            const float4 v = WR[j];                                               \
            ushort4 u;                                                            \
            u.x = f2bf(v.x); u.y = f2bf(v.y); u.z = f2bf(v.z); u.w = f2bf(v.w);   \
            *(ushort4*)&sm.wl[buf][crow * 72 + wcg + 4 * j] = u;                  \
        }                                                                         \
        if ((CH) + 2 < 16) {                                                      \
            const int c0 = ((CH) + 2) * 64;                                       \
            XR[0] = IO<T>::ld4(&x[xb + (size_t)(c0 + crow)      * PP + pxg]);     \
            XR[1] = IO<T>::ld4(&x[xb + (size_t)(c0 + crow + 32) * PP + pxg]);     \
            WR[0] = IO<T>::ld4(&w[crow * CC + c0 + wcg]);                         \
            WR[1] = IO<T>::ld4(&w[crow * CC + c0 + wcg + 4]);                     \
        }                                                                         \
        wg_sync_fast();                                                           \
        _Pragma("unroll")                                                         \
        for (int ks = 0; ks < 2; ++ks) {                                          \
            const bf16x8 av = *(const bf16x8*)&sm.xt[buf][(mt * 16 + l15) * 72 + ks * 32 + quad * 8]; \
            const bf16x8 bv = *(const bf16x8*)&sm.wl[buf][(nt * 16 + l15) * 72 + ks * 32 + quad * 8]; \
            acc = __builtin_amdgcn_mfma_f32_16x16x32_bf16(av, bv, acc, 0, 0, 0);  \
        }                                                                         \
    } while (0)

    #pragma unroll
    for (int chp = 0; chp < 8; ++chp) {
        ATTN_STEP(2 * chp,     xr0, wr0);
        ATTN_STEP(2 * chp + 1, xr1, wr1);
    }
#undef ATTN_STEP

    // reduce sumsq: red[c-row][px]
    sm.red[crow * 32 + pxg + 0] = ss0;
    sm.red[crow * 32 + pxg + 1] = ss1;
    sm.red[crow * 32 + pxg + 2] = ss2;
    sm.red[crow * 32 + pxg + 3] = ss3;
    __syncthreads();
    if (t < 32) {
        float s = 0.f;
        #pragma unroll
        for (int g = 0; g < 32; ++g) s += sm.red[g * 32 + t];
        const float r = 1.0f / fmaxf(sqrtf(s), EPSF);
        sm.rnorm[t] = r;
        rnorm_ws[n * PP + pbase + t] = r;
    }
    __syncthreads();
    // logits (scaled by rnorm) -> LDS: row=px(local), col=k
    #pragma unroll
    for (int reg = 0; reg < 4; ++reg) {
        const int px = mt * 16 + quad * 4 + reg;
        sm.lg[px * 33 + nt * 16 + l15] = acc[reg] * sm.rnorm[px];
    }
    __syncthreads();
    if (t < 32) {
        float m = -1e30f;
        #pragma unroll
        for (int k = 0; k < KK; ++k) m = fmaxf(m, sm.lg[t * 33 + k]);
        float s = 0.f;
        #pragma unroll
        for (int k = 0; k < KK; ++k) {
            const float e = expf(sm.lg[t * 33 + k] - m);
            sm.lg[t * 33 + k] = e;
            s += e;
        }
        sm.inv[t] = 1.0f / s;
    }
    __syncthreads();
    // write attn bf16 (thread: k=t>>3, 4 px) + asum partial (non-atomic)
    {
        const int k = t >> 3;
        ushort4 u;
        float vv[4];
        #pragma unroll
        for (int j = 0; j < 4; ++j) {
            const int px = pxg + j;
            vv[j] = sm.lg[px * 33 + k] * sm.inv[px];
        }
        u.x = f2bf(vv[0]); u.y = f2bf(vv[1]); u.z = f2bf(vv[2]); u.w = f2bf(vv[3]);
        float s = bf2f(u.x) + bf2f(u.y) + bf2f(u.z) + bf2f(u.w);
        *(ushort4*)&attn_g[((size_t)n * KK + k) * PP + pbase + pxg] = u;
        s += __shfl_xor(s, 1, 64);
        s += __shfl_xor(s, 2, 64);
        s += __shfl_xor(s, 4, 64);
        if ((t & 7) == 0) asum_part[(n * 32 + pt) * KK + k] = s;
    }
}

__global__ __launch_bounds__(256) void k_attn(const void* __restrict__ x,
                                              const void* __restrict__ w,
                                              int* __restrict__ flag,
                                              float* __restrict__ rnorm_ws,
                                              unsigned short* __restrict__ attn_g,
                                              float* __restrict__ asum_part) {
    __shared__ AttnSmem sm;
    __shared__ int s_bad;
    const int t = threadIdx.x;
    if (t == 0) s_bad = 0;
    __syncthreads();
    // per-block dtype detect (same 8KB prefix for all blocks -> L2 broadcast)
    const unsigned short* xu = (const unsigned short*)x;
    int bad = 0;
    for (int i = t; i < 4096; i += 256)
        if (((xu[i] >> 7) & 0xFFu) > 0x9Fu) bad = 1;
    if (bad) atomicOr(&s_bad, 1);
    __syncthreads();
    const int f = s_bad;
    if (blockIdx.x == 0 && t == 0) flag[0] = f;   // publish for k_vlad/k_out
    if (f) attn_body<float>((const float*)x, (const float*)w, rnorm_ws, attn_g, asum_part, sm);
    else   attn_body<unsigned short>((const unsigned short*)x, (const unsigned short*)w,
                                     rnorm_ws, attn_g, asum_part, sm);
}

// ---------------------------------------------------------------------------
// K2 (k_vlad): per (n, 32-c tile): MFMA vlad (M=32k, N=32c, Kdim=1024p).
// 16 chunks of 64p, double-buffered LDS, depth-2 register prefetch.
// A=attn[k][p] bf16, B=x*rnorm[c][p] bf16. Epilogue: -asum*cent, write vlad
// fp32, ssq partial store. grid 512 = n*32 + ct, block 256.
// ---------------------------------------------------------------------------
struct VladSmem {
    unsigned short xt[2][32 * 72];   // [buf][c][p]
    unsigned short at[2][32 * 72];   // [buf][k][p]
    float asum[32];
    float ssq[32];
};

template <typename T>
__device__ __forceinline__ void vlad_body(const T* __restrict__ x,
                                          const T* __restrict__ cent,
                                          const float* __restrict__ rnorm_ws,
                                          const unsigned short* __restrict__ attn_g,
                                          const float* __restrict__ asum_part,
                                          float* __restrict__ vlad,
                                          float* __restrict__ ssq_part,
                                          VladSmem& sm) {
    const int b = blockIdx.x, t = threadIdx.x;
    const int n = b >> 5, ct = b & 31, cbase = ct * 32;
    const int lane = t & 63, wid = t >> 6;
    const int quad = lane >> 4, l15 = lane & 15;
    const int mt = wid & 1, nt = wid >> 1;   // wave -> (k-half, c-half)

    if (t < 32) {
        float s = 0.f;
        #pragma unroll
        for (int pt = 0; pt < 32; ++pt) s += asum_part[(n * 32 + pt) * KK + t];
        sm.asum[t] = s;
        sm.ssq[t] = 0.f;
    }

    f32x4 acc = {0.f, 0.f, 0.f, 0.f};
    const size_t xb = (size_t)n * CC * PP + (size_t)cbase * PP;

    const int ak  = t >> 3, apg = (t & 7) * 8;   // attn staging: k-row, 8 p
    const int xpg = 4 * (t & 15);                // x staging: 4 p
    const int xc  = t >> 4;                      // x staging: c-row 0..15 (+16)
    const size_t ab = ((size_t)n * KK + ak) * PP + apg;

    uint4 ar0, ar1; float4 xr0[2], xr1[2], rn0, rn1;
    ar0 = *(const uint4*)&attn_g[ab];
    rn0 = *(const float4*)&rnorm_ws[n * PP + xpg];
    xr0[0] = IO<T>::ld4(&x[xb + (size_t)(xc)      * PP + xpg]);
    xr0[1] = IO<T>::ld4(&x[xb + (size_t)(xc + 16) * PP + xpg]);
    ar1 = *(const uint4*)&attn_g[ab + 64];
    rn1 = *(const float4*)&rnorm_ws[n * PP + 64 + xpg];
    xr1[0] = IO<T>::ld4(&x[xb + (size_t)(xc)      * PP + 64 + xpg]);
    xr1[1] = IO<T>::ld4(&x[xb + (size_t)(xc + 16) * PP + 64 + xpg]);

#define VLAD_STEP(CH, AR, XR, RN)                                                 \
    do {                                                                          \
        const int buf = (CH) & 1;                                                 \
        *(uint4*)&sm.at[buf][ak * 72 + apg] = AR;                                 \
        _Pragma("unroll")                                                         \
        for (int pass = 0; pass < 2; ++pass) {                                    \
            const int ci = xc + 16 * pass;                                        \
            const float4 v = XR[pass];                                            \
            ushort4 u;                                                            \
            u.x = f2bf(v.x * RN.x); u.y = f2bf(v.y * RN.y);                       \
            u.z = f2bf(v.z * RN.z); u.w = f2bf(v.w * RN.w);                       \
            *(ushort4*)&sm.xt[buf][ci * 72 + xpg] = u;                            \
        }                                                                         \
        if ((CH) + 2 < 16) {                                                      \
            const int p0 = ((CH) + 2) * 64;                                       \
            AR = *(const uint4*)&attn_g[ab + p0];                                 \
            RN = *(const float4*)&rnorm_ws[n * PP + p0 + xpg];                    \
            XR[0] = IO<T>::ld4(&x[xb + (size_t)(xc)      * PP + p0 + xpg]);       \
            XR[1] = IO<T>::ld4(&x[xb + (size_t)(xc + 16) * PP + p0 + xpg]);       \
        }                                                                         \
        wg_sync_fast();                                                           \
        _Pragma("unroll")                                                         \
        for (int ks = 0; ks < 2; ++ks) {                                          \
            const bf16x8 av = *(const bf16x8*)&sm.at[buf][(mt * 16 + l15) * 72 + ks * 32 + quad * 8]; \
            const bf16x8 bv = *(const bf16x8*)&sm.xt[buf][(nt * 16 + l15) * 72 + ks * 32 + quad * 8]; \
            acc = __builtin_amdgcn_mfma_f32_16x16x32_bf16(av, bv, acc, 0, 0, 0);  \
        }                                                                         \
    } while (0)

    #pragma unroll
    for (int pcp = 0; pcp < 8; ++pcp) {
        VLAD_STEP(2 * pcp,     ar0, xr0, rn0);
        VLAD_STEP(2 * pcp + 1, ar1, xr1, rn1);
    }
#undef VLAD_STEP

    // epilogue: D row = k(local), col = c(local)
    const int cg = cbase + nt * 16 + l15;
    #pragma unroll
    for (int reg = 0; reg < 4; ++reg) {
        const int k = mt * 16 + quad * 4 + reg;
        const float A = sm.asum[k];
        const float v0 = acc[reg] - A * IO<T>::ld(&cent[k * CC + cg]);
        vlad[((size_t)n * KK + k) * CC + cg] = v0;
        float s = v0 * v0;
        s += __shfl_xor(s, 1, 64);
        s += __shfl_xor(s, 2, 64);
        s += __shfl_xor(s, 4, 64);
        s += __shfl_xor(s, 8, 64);
        if (l15 == 0) atomicAdd(&sm.ssq[k], s);
    }
    __syncthreads();
    if (t < 32) ssq_part[(n * 32 + ct) * KK + t] = sm.ssq[t];
}

__global__ __launch_bounds__(256) void k_vlad(const void* __restrict__ x,
                                              const void* __restrict__ cent,
                                              const int* __restrict__ flag,
                                              const float* __restrict__ rnorm_ws,
                                              const unsigned short* __restrict__ attn_g,
                                              const float* __restrict__ asum_part,
                                              float* __restrict__ vlad,
                                              float* __restrict__ ssq_part) {
    __shared__ VladSmem sm;
    if (*flag) vlad_body<float>((const float*)x, (const float*)cent, rnorm_ws, attn_g,
                                asum_part, vlad, ssq_part, sm);
    else       vlad_body<unsigned short>((const unsigned short*)x, (const unsigned short*)cent,
                                         rnorm_ws, attn_g, asum_part, vlad, ssq_part, sm);
}

// ---------------------------------------------------------------------------
// K3 (k_out): reduce ssq partials (32 L2-hot loads x 32 threads), factors,
// then out = vlad * rintra * rglob cast to out dtype. grid N*K, 256 thr.
// ---------------------------------------------------------------------------
__global__ __launch_bounds__(256) void k_out(const float* __restrict__ vlad,
                                             const float* __restrict__ ssq_part,
                                             const int* __restrict__ flag,
                                             void* __restrict__ out) {
    __shared__ float fsh;
    const int b = blockIdx.x, t = threadIdx.x;
    const int n = b >> 5, k = b & 31;
    if (t < 64) {
        float s = 0.f;
        if (t < 32) {
            #pragma unroll
            for (int ct = 0; ct < 32; ++ct) s += ssq_part[(n * 32 + ct) * KK + t];
        }
        const float r = 1.0f / fmaxf(sqrtf(s), EPSF);
        float g = s * r * r;
        #pragma unroll
        for (int off = 32; off > 0; off >>= 1) g += __shfl_down(g, off, 64);
        const float rk = __shfl(r, k, 64);
        if (t == 0) fsh = rk * (1.0f / fmaxf(sqrtf(g), EPSF));
    }
    __syncthreads();
    const float f = fsh;
    const float4 v = ((const float4*)(vlad + (size_t)b * CC))[t];
    if (*flag) {
        float4 o; o.x = v.x * f; o.y = v.y * f; o.z = v.z * f; o.w = v.w * f;
        ((float4*)((float*)out + (size_t)b * CC))[t] = o;
    } else {
        ushort4 u;
        u.x = f2bf(v.x * f); u.y = f2bf(v.y * f);
        u.z = f2bf(v.z * f); u.w = f2bf(v.w * f);
        ((ushort4*)((unsigned short*)out + (size_t)b * CC))[t] = u;
    }
}

extern "C" void kernel_launch(void* const* d_in, const int* in_sizes, int n_in,
                              void* d_out, int out_size, void* d_ws, size_t ws_size,
                              hipStream_t stream) {
    const void* x    = d_in[0];
    const void* w    = d_in[1];
    const void* cent = d_in[2];

    float* ws        = (float*)d_ws;
    float* rnorm_ws  = ws;                              // 16384 floats
    float* vlad      = rnorm_ws + NB * PP;              // 524288
    float* asum_part = vlad + NB * KK * CC;             // 16384 (n,pt,k)
    float* ssq_part  = asum_part + NB * 32 * KK;        // 16384 (n,ct,k)
    int*   flag      = (int*)(ssq_part + NB * 32 * KK); // 1 (+ pad)
    unsigned short* attn_g = (unsigned short*)(flag + 4);  // 512K ushorts

    k_attn<<<NB * 32, 256, 0, stream>>>(x, w, flag, rnorm_ws, attn_g, asum_part);
    k_vlad<<<NB * 32, 256, 0, stream>>>(x, cent, flag, rnorm_ws, attn_g, asum_part, vlad, ssq_part);
    k_out<<<NB * KK, 256, 0, stream>>>(vlad, ssq_part, flag, d_out);
}